// Round 4
// baseline (380.506 us; speedup 1.0000x reference)
//
#include <hip/hip_runtime.h>
#include <math.h>

// GATConv forward:
//   k_cast_w    : Wbf[n][k] = bf16(W[n][k])  (B^T layout for feat @ W.T)
//   k_gemm_mfma : feat_src(bf16) = feat @ W.T via mfma_f32_16x16x32_bf16.
//                 fp32 A loaded per-block, converted bf16 in-register (RNE),
//                 XOR-swizzled LDS tile, BK=64 double-buffered, one barrier
//                 per chunk. B straight from L2-hot Wbf. Fused el/er.
//                 Outputs are HEAD-MAJOR: fs_h[h][node][64], el_h/er_h[h][node]
//                 so the aggregate can partition the working set by head.
//   k_aggregate : per-dst edge softmax + weighted bf16 gather-sum,
//                 HEAD-PARTITIONED + XCD-PINNED. blockIdx%8 -> head pair, so
//                 with round-robin block->XCD dispatch each XCD gathers from
//                 a single 12.8 MB head slice instead of the full 51.2 MB
//                 table. Round-3 FETCH (443 MB) == per-XCD replication floor
//                 (51.2*8 + col_ind + el/er); this cuts the replicated bytes
//                 4x. Mapping is a locality heuristic only -- correctness does
//                 not depend on it.
//
// N=100000, IN=256, H=4, D=64, E=N*16; degree uniformly 16 (row_ptr=arange*16).

#define HEADS 4
#define KIN 256
#define NOUT 256   // H*D
#define NEG_SLOPE 0.2f

typedef __attribute__((ext_vector_type(4))) short short4v;
typedef __attribute__((ext_vector_type(8))) short short8v;
typedef __attribute__((ext_vector_type(4))) float floatx4;

static __device__ __forceinline__ unsigned short f2bf(float x) {
  // round-to-nearest-even fp32 -> bf16 (inputs are normal; no NaN handling)
  unsigned u = __float_as_uint(x);
  u += 0x7FFFu + ((u >> 16) & 1u);
  return (unsigned short)(u >> 16);
}
static __device__ __forceinline__ float bf2f(unsigned short b) {
  return __uint_as_float(((unsigned)b) << 16);
}

__global__ __launch_bounds__(256) void k_cast_w(const float* __restrict__ W,
                                                unsigned short* __restrict__ Wbf) {
  const int i = blockIdx.x * 256 + threadIdx.x;  // float4 index, 16384 total
  float4 f = ((const float4*)W)[i];
  ushort4 o;
  o.x = f2bf(f.x); o.y = f2bf(f.y); o.z = f2bf(f.z); o.w = f2bf(f.w);
  ((ushort4*)Wbf)[i] = o;
}

// Block = 256 threads = 4 waves. Block tile: M=64 rows, N=256 (full width).
// Wave w owns cols [64w, 64w+64) == head w. Per wave: 4x4 grid of 16x16 MFMA
// tiles, K in 4 chunks of 64 (2 MFMA k-steps each).
//
// A LDS: bf16 [64 rows][64 k] per buffer (8 KB), 16B granule j of row r stored
// at granule j ^ (r&7)  -> the stride-128B fragment read (16 lanes, same k-
// granule, consecutive rows) spreads across all banks (2-way alias only).
__global__ __launch_bounds__(256, 2) void k_gemm_mfma(
    const float* __restrict__ feat, const unsigned short* __restrict__ Wbf,
    const float* __restrict__ attn_l, const float* __restrict__ attn_r,
    unsigned short* __restrict__ fs_h, float* __restrict__ el_h,
    float* __restrict__ er_h, int n_nodes) {
  __shared__ unsigned short Alds[2][64 * 64];  // 2 x 8 KB bf16

  const int tid = threadIdx.x;
  const int lane = tid & 63;
  const int w = tid >> 6;      // wave = head = col-group
  const int m0 = blockIdx.x * 64;
  const int q = lane >> 4;     // quad 0..3
  const int l15 = lane & 15;

  floatx4 acc[4][4];
#pragma unroll
  for (int mt = 0; mt < 4; ++mt)
#pragma unroll
    for (int nt = 0; nt < 4; ++nt)
#pragma unroll
      for (int r = 0; r < 4; ++r) acc[mt][nt][r] = 0.0f;

  // ---- A staging map: thread t -> row ar = t>>2, float window (t&3)*16..+16
  // (4 coalesced float4 loads per chunk); owns bf16 granules 2(t&3), 2(t&3)+1.
  const int ar = tid >> 2;
  const int aj = tid & 3;
  const int r7 = ar & 7;
  int agr = m0 + ar;
  if (agr >= n_nodes) agr = n_nodes - 1;  // clamp tail (rows unused below)
  const float* __restrict__ abase = feat + (size_t)agr * KIN + aj * 16;
  unsigned short* const aw0 = &Alds[0][ar * 64 + ((2 * aj + 0) ^ r7) * 8];
  unsigned short* const aw1 = &Alds[0][ar * 64 + ((2 * aj + 1) ^ r7) * 8];
  const int bufoff = 64 * 64;  // elems between buffer 0 and 1

  float4 rg[2][4];  // two reg-staging buffers (indices fold: loop is unrolled)

#pragma unroll
  for (int i = 0; i < 4; ++i) rg[0][i] = *(const float4*)(abase + i * 4);

#pragma unroll
  for (int kc = 0; kc < 4; ++kc) {
    const int b = kc & 1;
    // ---- convert + swizzled LDS write of chunk kc from regs
    {
      const float4* R = rg[b];
      short8v g0, g1;
      g0[0] = (short)f2bf(R[0].x); g0[1] = (short)f2bf(R[0].y);
      g0[2] = (short)f2bf(R[0].z); g0[3] = (short)f2bf(R[0].w);
      g0[4] = (short)f2bf(R[1].x); g0[5] = (short)f2bf(R[1].y);
      g0[6] = (short)f2bf(R[1].z); g0[7] = (short)f2bf(R[1].w);
      g1[0] = (short)f2bf(R[2].x); g1[1] = (short)f2bf(R[2].y);
      g1[2] = (short)f2bf(R[2].z); g1[3] = (short)f2bf(R[2].w);
      g1[4] = (short)f2bf(R[3].x); g1[5] = (short)f2bf(R[3].y);
      g1[6] = (short)f2bf(R[3].z); g1[7] = (short)f2bf(R[3].w);
      *(short8v*)(aw0 + b * bufoff) = g0;
      *(short8v*)(aw1 + b * bufoff) = g1;
    }
    // ---- issue next chunk's global loads (latency hides under barrier+MFMA)
    if (kc < 3) {
      const float* p = abase + (kc + 1) * 64;
#pragma unroll
      for (int i = 0; i < 4; ++i) rg[(kc + 1) & 1][i] = *(const float4*)(p + i * 4);
    }
    __syncthreads();  // chunk kc visible to all; prev buffer free for reuse

    // ---- B fragments straight from L2-hot Wbf:
    // lane(q,l15) needs B[n = 64w+16nt+l15][k = 64kc+32ks+8q .. +8]
    short8v bfr[2][4];
#pragma unroll
    for (int ks = 0; ks < 2; ++ks)
#pragma unroll
      for (int nt = 0; nt < 4; ++nt)
        bfr[ks][nt] = *(const short8v*)(Wbf + (size_t)(w * 64 + nt * 16 + l15) * KIN +
                                        kc * 64 + ks * 32 + q * 8);

#pragma unroll
    for (int ks = 0; ks < 2; ++ks) {
      short8v af[4];
#pragma unroll
      for (int mt = 0; mt < 4; ++mt) {
        const int slot = (ks * 4 + q) ^ (l15 & 7);  // un-swizzle on read
        af[mt] = *(const short8v*)(&Alds[b][(mt * 16 + l15) * 64 + slot * 8]);
      }
#pragma unroll
      for (int mt = 0; mt < 4; ++mt)
#pragma unroll
        for (int nt = 0; nt < 4; ++nt)
          acc[mt][nt] = __builtin_amdgcn_mfma_f32_16x16x32_bf16(
              af[mt], bfr[ks][nt], acc[mt][nt], 0, 0, 0);
    }
  }

  // ---- epilogue: C/D layout col = l15, row = q*4 + r (per 16x16 tile).
  // Store feat_src head-major (bf16) + el_h/er_h from fp32 accumulators.
  float alv[4], arv[4];
#pragma unroll
  for (int nt = 0; nt < 4; ++nt) {
    alv[nt] = attn_l[w * 64 + nt * 16 + l15];
    arv[nt] = attn_r[w * 64 + nt * 16 + l15];
  }
#pragma unroll
  for (int mt = 0; mt < 4; ++mt) {
#pragma unroll
    for (int r = 0; r < 4; ++r) {
      const int m = m0 + mt * 16 + q * 4 + r;
      const bool mvalid = (m < n_nodes);
      float pl = 0.f, pr = 0.f;
#pragma unroll
      for (int nt = 0; nt < 4; ++nt) {
        const float v = acc[mt][nt][r];
        pl = fmaf(v, alv[nt], pl);
        pr = fmaf(v, arv[nt], pr);
        if (mvalid)
          fs_h[((size_t)w * n_nodes + m) * 64 + nt * 16 + l15] = f2bf(v);
      }
      // reduce over the 16 lanes of this quad (same row m)
#pragma unroll
      for (int off = 1; off < 16; off <<= 1) {
        pl += __shfl_xor(pl, off, 64);
        pr += __shfl_xor(pr, off, 64);
      }
      if (l15 == 0 && mvalid) {
        el_h[(size_t)w * n_nodes + m] = pl;
        er_h[(size_t)w * n_nodes + m] = pr;
      }
    }
  }
}

// Head-partitioned aggregate. One wave = one (node, head) unit; block = 4
// consecutive nodes, ONE head. Block->head mapping pins each head pair to a
// fixed blockIdx%8 residue so round-robin XCD dispatch keeps each XCD on one
// 12.8 MB head slice.
//   phase 1 (softmax): j = lane&15 over the 16 edges (replicated x4, no
//                      divergence; redundant loads hit L1).
//   phase 2 (gather):  pass p in {0,1}: lane = e8*8 + c covers 8 edges x
//                      16B granules of the 128B head row; 3-step shfl_xor
//                      tree over e8; lanes 0-7 store the 256B output slice.
__global__ __launch_bounds__(256, 4) void k_aggregate(
    const int* __restrict__ row_ptr, const int* __restrict__ col_ind,
    const float* __restrict__ el_h, const float* __restrict__ er_h,
    const unsigned short* __restrict__ fs_h, float* __restrict__ out,
    int n_nodes) {
  const int bid = blockIdx.x;
  const int lane = threadIdx.x & 63;
  const int w = threadIdx.x >> 6;
  const int x = bid & 7;
  const int h = x >> 1;                      // head: residues {2h, 2h+1}
  const int idx = (bid >> 3) * 2 + (x & 1);  // node-group within head
  const int node = idx * 4 + w;
  if (node >= n_nodes) return;

  const int j = lane & 15;
  const int rs = row_ptr[node];
  const int deg = row_ptr[node + 1] - rs;  // == 16 by construction
  const bool valid = (j < deg);
  const int src = valid ? col_ind[rs + j] : 0;

  const size_t hN = (size_t)h * n_nodes;
  float e = valid ? (er_h[hN + src] + el_h[hN + node]) : -INFINITY;
  e = (e > 0.f) ? e : NEG_SLOPE * e;  // LeakyReLU

  float mx = e;
#pragma unroll
  for (int off = 1; off < 16; off <<= 1) mx = fmaxf(mx, __shfl_xor(mx, off, 64));
  float ex = valid ? __expf(e - mx) : 0.f;
  float s = ex;
#pragma unroll
  for (int off = 1; off < 16; off <<= 1) s += __shfl_xor(s, off, 64);
  const float a = ex / s;  // a == 0 for invalid edges (ex == 0)

  // ---- phase 2: two-pass gather over the 128B head rows (hoisted loads)
  const int e8 = lane >> 3;  // edge-within-pass
  const int c = lane & 7;    // 16B granule within the row
  const int s0 = __shfl(src, e8, 64);
  const int s1 = __shfl(src, 8 + e8, 64);
  const float w0 = __shfl(a, e8, 64);
  const float w1 = __shfl(a, 8 + e8, 64);
  const uint4 u0 = ((const uint4*)(fs_h + (hN + (size_t)s0) * 64))[c];
  const uint4 u1 = ((const uint4*)(fs_h + (hN + (size_t)s1) * 64))[c];

  float acc[8];
#pragma unroll
  for (int k = 0; k < 8; ++k) acc[k] = 0.f;
  acc[0] = fmaf(w0, __uint_as_float(u0.x << 16), acc[0]);
  acc[1] = fmaf(w0, __uint_as_float(u0.x & 0xFFFF0000u), acc[1]);
  acc[2] = fmaf(w0, __uint_as_float(u0.y << 16), acc[2]);
  acc[3] = fmaf(w0, __uint_as_float(u0.y & 0xFFFF0000u), acc[3]);
  acc[4] = fmaf(w0, __uint_as_float(u0.z << 16), acc[4]);
  acc[5] = fmaf(w0, __uint_as_float(u0.z & 0xFFFF0000u), acc[5]);
  acc[6] = fmaf(w0, __uint_as_float(u0.w << 16), acc[6]);
  acc[7] = fmaf(w0, __uint_as_float(u0.w & 0xFFFF0000u), acc[7]);
  acc[0] = fmaf(w1, __uint_as_float(u1.x << 16), acc[0]);
  acc[1] = fmaf(w1, __uint_as_float(u1.x & 0xFFFF0000u), acc[1]);
  acc[2] = fmaf(w1, __uint_as_float(u1.y << 16), acc[2]);
  acc[3] = fmaf(w1, __uint_as_float(u1.y & 0xFFFF0000u), acc[3]);
  acc[4] = fmaf(w1, __uint_as_float(u1.z << 16), acc[4]);
  acc[5] = fmaf(w1, __uint_as_float(u1.z & 0xFFFF0000u), acc[5]);
  acc[6] = fmaf(w1, __uint_as_float(u1.w << 16), acc[6]);
  acc[7] = fmaf(w1, __uint_as_float(u1.w & 0xFFFF0000u), acc[7]);

  // tree-reduce over e8 (lane bits 3..5); result replicated per 8-lane group
#pragma unroll
  for (int off = 8; off < 64; off <<= 1)
#pragma unroll
    for (int k = 0; k < 8; ++k) acc[k] += __shfl_xor(acc[k], off, 64);

  if (lane < 8) {
    float* op = out + ((size_t)node * HEADS + h) * 64 + lane * 8;
    *(float4*)op = make_float4(acc[0], acc[1], acc[2], acc[3]);
    *(float4*)(op + 4) = make_float4(acc[4], acc[5], acc[6], acc[7]);
  }
}

extern "C" void kernel_launch(void* const* d_in, const int* in_sizes, int n_in,
                              void* d_out, int out_size, void* d_ws, size_t ws_size,
                              hipStream_t stream) {
  const int* row_ptr = (const int*)d_in[0];
  const int* col_ind = (const int*)d_in[1];
  const float* feat = (const float*)d_in[2];
  const float* W = (const float*)d_in[3];
  const float* attn_l = (const float*)d_in[4];
  const float* attn_r = (const float*)d_in[5];
  float* out = (float*)d_out;
  const int n_nodes = in_sizes[0] - 1;

  // Workspace: Wbf (128 KB) | fs_h bf16 [H][N][64] (51.2 MB) | el_h, er_h
  // [H][N] (1.6 MB each)
  char* ws = (char*)d_ws;
  unsigned short* Wbf = (unsigned short*)ws;
  unsigned short* fs_h = (unsigned short*)(ws + 128 * 1024);
  size_t fs_bytes = (size_t)n_nodes * NOUT * sizeof(unsigned short);
  float* el_h = (float*)(ws + 128 * 1024 + fs_bytes);
  float* er_h = el_h + (size_t)n_nodes * HEADS;

  k_cast_w<<<64, 256, 0, stream>>>(W, Wbf);
  k_gemm_mfma<<<(n_nodes + 63) / 64, 256, 0, stream>>>(
      feat, Wbf, attn_l, attn_r, fs_h, el_h, er_h, n_nodes);

  int nb_per_head = (n_nodes + 3) / 4;
  nb_per_head += (nb_per_head & 1);  // even, so grid%8==0 and mapping is exact
  k_aggregate<<<nb_per_head * 4, 256, 0, stream>>>(
      row_ptr, col_ind, el_h, er_h, fs_h, out, n_nodes);
}

// Round 6
// 340.641 us; speedup vs baseline: 1.1170x; 1.1170x over previous
//
#include <hip/hip_runtime.h>
#include <math.h>

// GATConv forward:
//   k_cast_w    : Wbf[n][k] = bf16(W[n][k])  (B^T layout for feat @ W.T)
//   k_gemm_mfma : feat_src(bf16) = feat @ W.T via mfma_f32_16x16x32_bf16.
//                 fp32 A loaded per-block, converted bf16 in-register (RNE),
//                 XOR-swizzled LDS tile, BK=64 double-buffered, one barrier
//                 per chunk. B straight from L2-hot Wbf. Fused el/er.
//                 Outputs HEAD-MAJOR: fs_h[h][node][64], el_h/er_h[h][node].
//   k_aggregate : per-dst edge softmax + weighted bf16 gather-sum.
//                 HEAD-PINNED (blockIdx%8 -> head pair; cut FETCH 443->318 MB
//                 in round 4) x 8-DEEP MLP (round 4 regressed 142->180 us
//                 because only 2 loads/wave were in flight; this restores the
//                 8-hoisted-dwordx4 pipeline AND 1x softmax): one wave = 4
//                 nodes x 1 head; 64 edges = 8 load instrs; static 4-way acc;
//                 3-step shfl_xor tree; lanes 0-31 store 1KB/wave contiguous.
//
// (Round 5 was an infra failure -- "container failed twice", bench never ran.
//  Source re-audited for OOB/hangs: none possible. Resubmitted unchanged.)
//
// N=100000, IN=256, H=4, D=64, E=N*16; degree uniformly 16 (row_ptr=arange*16).

#define HEADS 4
#define KIN 256
#define NOUT 256   // H*D
#define NEG_SLOPE 0.2f

typedef __attribute__((ext_vector_type(4))) short short4v;
typedef __attribute__((ext_vector_type(8))) short short8v;
typedef __attribute__((ext_vector_type(4))) float floatx4;

static __device__ __forceinline__ unsigned short f2bf(float x) {
  // round-to-nearest-even fp32 -> bf16 (inputs are normal; no NaN handling)
  unsigned u = __float_as_uint(x);
  u += 0x7FFFu + ((u >> 16) & 1u);
  return (unsigned short)(u >> 16);
}
static __device__ __forceinline__ float bf2f(unsigned short b) {
  return __uint_as_float(((unsigned)b) << 16);
}

__global__ __launch_bounds__(256) void k_cast_w(const float* __restrict__ W,
                                                unsigned short* __restrict__ Wbf) {
  const int i = blockIdx.x * 256 + threadIdx.x;  // float4 index, 16384 total
  float4 f = ((const float4*)W)[i];
  ushort4 o;
  o.x = f2bf(f.x); o.y = f2bf(f.y); o.z = f2bf(f.z); o.w = f2bf(f.w);
  ((ushort4*)Wbf)[i] = o;
}

// Block = 256 threads = 4 waves. Block tile: M=64 rows, N=256 (full width).
// Wave w owns cols [64w, 64w+64) == head w. Per wave: 4x4 grid of 16x16 MFMA
// tiles, K in 4 chunks of 64 (2 MFMA k-steps each).
//
// A LDS: bf16 [64 rows][64 k] per buffer (8 KB), 16B granule j of row r stored
// at granule j ^ (r&7)  -> the stride-128B fragment read (16 lanes, same k-
// granule, consecutive rows) spreads across all banks (2-way alias only).
__global__ __launch_bounds__(256, 2) void k_gemm_mfma(
    const float* __restrict__ feat, const unsigned short* __restrict__ Wbf,
    const float* __restrict__ attn_l, const float* __restrict__ attn_r,
    unsigned short* __restrict__ fs_h, float* __restrict__ el_h,
    float* __restrict__ er_h, int n_nodes) {
  __shared__ unsigned short Alds[2][64 * 64];  // 2 x 8 KB bf16

  const int tid = threadIdx.x;
  const int lane = tid & 63;
  const int w = tid >> 6;      // wave = head = col-group
  const int m0 = blockIdx.x * 64;
  const int q = lane >> 4;     // quad 0..3
  const int l15 = lane & 15;

  floatx4 acc[4][4];
#pragma unroll
  for (int mt = 0; mt < 4; ++mt)
#pragma unroll
    for (int nt = 0; nt < 4; ++nt)
#pragma unroll
      for (int r = 0; r < 4; ++r) acc[mt][nt][r] = 0.0f;

  // ---- A staging map: thread t -> row ar = t>>2, float window (t&3)*16..+16
  // (4 coalesced float4 loads per chunk); owns bf16 granules 2(t&3), 2(t&3)+1.
  const int ar = tid >> 2;
  const int aj = tid & 3;
  const int r7 = ar & 7;
  int agr = m0 + ar;
  if (agr >= n_nodes) agr = n_nodes - 1;  // clamp tail (rows unused below)
  const float* __restrict__ abase = feat + (size_t)agr * KIN + aj * 16;
  unsigned short* const aw0 = &Alds[0][ar * 64 + ((2 * aj + 0) ^ r7) * 8];
  unsigned short* const aw1 = &Alds[0][ar * 64 + ((2 * aj + 1) ^ r7) * 8];
  const int bufoff = 64 * 64;  // elems between buffer 0 and 1

  float4 rg[2][4];  // two reg-staging buffers (indices fold: loop is unrolled)

#pragma unroll
  for (int i = 0; i < 4; ++i) rg[0][i] = *(const float4*)(abase + i * 4);

#pragma unroll
  for (int kc = 0; kc < 4; ++kc) {
    const int b = kc & 1;
    // ---- convert + swizzled LDS write of chunk kc from regs
    {
      const float4* R = rg[b];
      short8v g0, g1;
      g0[0] = (short)f2bf(R[0].x); g0[1] = (short)f2bf(R[0].y);
      g0[2] = (short)f2bf(R[0].z); g0[3] = (short)f2bf(R[0].w);
      g0[4] = (short)f2bf(R[1].x); g0[5] = (short)f2bf(R[1].y);
      g0[6] = (short)f2bf(R[1].z); g0[7] = (short)f2bf(R[1].w);
      g1[0] = (short)f2bf(R[2].x); g1[1] = (short)f2bf(R[2].y);
      g1[2] = (short)f2bf(R[2].z); g1[3] = (short)f2bf(R[2].w);
      g1[4] = (short)f2bf(R[3].x); g1[5] = (short)f2bf(R[3].y);
      g1[6] = (short)f2bf(R[3].z); g1[7] = (short)f2bf(R[3].w);
      *(short8v*)(aw0 + b * bufoff) = g0;
      *(short8v*)(aw1 + b * bufoff) = g1;
    }
    // ---- issue next chunk's global loads (latency hides under barrier+MFMA)
    if (kc < 3) {
      const float* p = abase + (kc + 1) * 64;
#pragma unroll
      for (int i = 0; i < 4; ++i) rg[(kc + 1) & 1][i] = *(const float4*)(p + i * 4);
    }
    __syncthreads();  // chunk kc visible to all; prev buffer free for reuse

    // ---- B fragments straight from L2-hot Wbf:
    // lane(q,l15) needs B[n = 64w+16nt+l15][k = 64kc+32ks+8q .. +8]
    short8v bfr[2][4];
#pragma unroll
    for (int ks = 0; ks < 2; ++ks)
#pragma unroll
      for (int nt = 0; nt < 4; ++nt)
        bfr[ks][nt] = *(const short8v*)(Wbf + (size_t)(w * 64 + nt * 16 + l15) * KIN +
                                        kc * 64 + ks * 32 + q * 8);

#pragma unroll
    for (int ks = 0; ks < 2; ++ks) {
      short8v af[4];
#pragma unroll
      for (int mt = 0; mt < 4; ++mt) {
        const int slot = (ks * 4 + q) ^ (l15 & 7);  // un-swizzle on read
        af[mt] = *(const short8v*)(&Alds[b][(mt * 16 + l15) * 64 + slot * 8]);
      }
#pragma unroll
      for (int mt = 0; mt < 4; ++mt)
#pragma unroll
        for (int nt = 0; nt < 4; ++nt)
          acc[mt][nt] = __builtin_amdgcn_mfma_f32_16x16x32_bf16(
              af[mt], bfr[ks][nt], acc[mt][nt], 0, 0, 0);
    }
  }

  // ---- epilogue: C/D layout col = l15, row = q*4 + r (per 16x16 tile).
  // Store feat_src head-major (bf16) + el_h/er_h from fp32 accumulators.
  float alv[4], arv[4];
#pragma unroll
  for (int nt = 0; nt < 4; ++nt) {
    alv[nt] = attn_l[w * 64 + nt * 16 + l15];
    arv[nt] = attn_r[w * 64 + nt * 16 + l15];
  }
#pragma unroll
  for (int mt = 0; mt < 4; ++mt) {
#pragma unroll
    for (int r = 0; r < 4; ++r) {
      const int m = m0 + mt * 16 + q * 4 + r;
      const bool mvalid = (m < n_nodes);
      float pl = 0.f, pr = 0.f;
#pragma unroll
      for (int nt = 0; nt < 4; ++nt) {
        const float v = acc[mt][nt][r];
        pl = fmaf(v, alv[nt], pl);
        pr = fmaf(v, arv[nt], pr);
        if (mvalid)
          fs_h[((size_t)w * n_nodes + m) * 64 + nt * 16 + l15] = f2bf(v);
      }
      // reduce over the 16 lanes of this quad (same row m)
#pragma unroll
      for (int off = 1; off < 16; off <<= 1) {
        pl += __shfl_xor(pl, off, 64);
        pr += __shfl_xor(pr, off, 64);
      }
      if (l15 == 0 && mvalid) {
        el_h[(size_t)w * n_nodes + m] = pl;
        er_h[(size_t)w * n_nodes + m] = pr;
      }
    }
  }
}

// Head-pinned aggregate, 4 nodes per wave. Block = 4 waves = 16 nodes x ONE
// head; blockIdx%8 residue -> head pair so round-robin XCD dispatch keeps each
// XCD on one 12.8 MB head slice (locality heuristic only).
//   phase 1 (softmax): lane = g*16 + j  (g = node-in-wave, j = edge). 16-lane
//                      shfl_xor reduce; NO replication.
//   phase 2 (gather):  8 hoisted dwordx4; instr p covers node p>>1, edges
//                      (p&1)*8+e8; lane = e8*8+c reads 16B granule c of the
//                      128B head row. Static per-node acc arrays; 3-step
//                      shfl_xor tree over e8; lanes 0-31 store 32B each
//                      (1KB contiguous per wave).
__global__ __launch_bounds__(256, 4) void k_aggregate(
    const int* __restrict__ row_ptr, const int* __restrict__ col_ind,
    const float* __restrict__ el_h, const float* __restrict__ er_h,
    const unsigned short* __restrict__ fs_h, float* __restrict__ out,
    int n_nodes) {
  const int bid = blockIdx.x;
  const int lane = threadIdx.x & 63;
  const int w = threadIdx.x >> 6;
  const int x = bid & 7;
  const int h = x >> 1;                      // head: residues {2h, 2h+1}
  const int idx = (bid >> 3) * 2 + (x & 1);  // 16-node group within head
  const int nbase = idx * 16 + w * 4;        // wave's first node

  // ---- phase 1: softmax. lane = g*16 + j
  const int g = lane >> 4;
  const int j = lane & 15;
  const int node = nbase + g;
  const int nclamp = (node < n_nodes) ? node : (n_nodes - 1);
  const int rs = row_ptr[nclamp];
  const int deg = row_ptr[nclamp + 1] - rs;  // == 16 by construction
  const bool valid = (node < n_nodes) && (j < deg);
  const int src = valid ? col_ind[rs + j] : 0;

  const size_t hN = (size_t)h * n_nodes;
  float e = valid ? (er_h[hN + src] + el_h[hN + nclamp]) : -INFINITY;
  e = (e > 0.f) ? e : NEG_SLOPE * e;  // LeakyReLU

  float mx = e;
#pragma unroll
  for (int off = 1; off < 16; off <<= 1) mx = fmaxf(mx, __shfl_xor(mx, off, 64));
  float ex = valid ? __expf(e - mx) : 0.f;
  float s = ex;
#pragma unroll
  for (int off = 1; off < 16; off <<= 1) s += __shfl_xor(s, off, 64);
  const float a = ex / s;  // a == 0 for invalid edges (ex == 0)

  // ---- phase 2: 8 hoisted loads. lane = e8*8 + c; edge eg = p*8+e8 lives at
  // source lane eg (since (eg>>4)*16 + (eg&15) == eg).
  const int e8 = lane >> 3;
  const int c = lane & 7;

  int sj[8];
#pragma unroll
  for (int p = 0; p < 8; ++p) sj[p] = __shfl(src, p * 8 + e8, 64);

  uint4 u[8];
#pragma unroll
  for (int p = 0; p < 8; ++p)
    u[p] = ((const uint4*)(fs_h + (hN + (size_t)sj[p]) * 64))[c];

  float wgt[8];
#pragma unroll
  for (int p = 0; p < 8; ++p) wgt[p] = __shfl(a, p * 8 + e8, 64);

  float ac0[8], ac1[8], ac2[8], ac3[8];
#pragma unroll
  for (int k = 0; k < 8; ++k) { ac0[k] = 0.f; ac1[k] = 0.f; ac2[k] = 0.f; ac3[k] = 0.f; }

#define ACCUM(A, p)                                          \
  do {                                                       \
    const uint4 v = u[p];                                    \
    const float w0 = wgt[p];                                 \
    A[0] = fmaf(w0, __uint_as_float(v.x << 16), A[0]);       \
    A[1] = fmaf(w0, __uint_as_float(v.x & 0xFFFF0000u), A[1]); \
    A[2] = fmaf(w0, __uint_as_float(v.y << 16), A[2]);       \
    A[3] = fmaf(w0, __uint_as_float(v.y & 0xFFFF0000u), A[3]); \
    A[4] = fmaf(w0, __uint_as_float(v.z << 16), A[4]);       \
    A[5] = fmaf(w0, __uint_as_float(v.z & 0xFFFF0000u), A[5]); \
    A[6] = fmaf(w0, __uint_as_float(v.w << 16), A[6]);       \
    A[7] = fmaf(w0, __uint_as_float(v.w & 0xFFFF0000u), A[7]); \
  } while (0)

  ACCUM(ac0, 0); ACCUM(ac0, 1);
  ACCUM(ac1, 2); ACCUM(ac1, 3);
  ACCUM(ac2, 4); ACCUM(ac2, 5);
  ACCUM(ac3, 6); ACCUM(ac3, 7);
#undef ACCUM

  // tree-reduce over e8 (lane bits 3..5); result replicated across all lanes
#pragma unroll
  for (int off = 8; off < 64; off <<= 1) {
#pragma unroll
    for (int k = 0; k < 8; ++k) {
      ac0[k] += __shfl_xor(ac0[k], off, 64);
      ac1[k] += __shfl_xor(ac1[k], off, 64);
      ac2[k] += __shfl_xor(ac2[k], off, 64);
      ac3[k] += __shfl_xor(ac3[k], off, 64);
    }
  }

  // ---- store: lanes 0..31, lane = sg*8 + sc -> node nbase+sg, granule sc
  if (lane < 32) {
    const int sg = lane >> 3;
    const int sc = lane & 7;
    const int sn = nbase + sg;
    if (sn < n_nodes) {
      float v[8];
#pragma unroll
      for (int k = 0; k < 8; ++k)
        v[k] = (sg & 2) ? ((sg & 1) ? ac3[k] : ac2[k])
                        : ((sg & 1) ? ac1[k] : ac0[k]);
      float* op = out + ((size_t)sn * HEADS + h) * 64 + sc * 8;
      *(float4*)op = make_float4(v[0], v[1], v[2], v[3]);
      *(float4*)(op + 4) = make_float4(v[4], v[5], v[6], v[7]);
    }
  }
}

extern "C" void kernel_launch(void* const* d_in, const int* in_sizes, int n_in,
                              void* d_out, int out_size, void* d_ws, size_t ws_size,
                              hipStream_t stream) {
  const int* row_ptr = (const int*)d_in[0];
  const int* col_ind = (const int*)d_in[1];
  const float* feat = (const float*)d_in[2];
  const float* W = (const float*)d_in[3];
  const float* attn_l = (const float*)d_in[4];
  const float* attn_r = (const float*)d_in[5];
  float* out = (float*)d_out;
  const int n_nodes = in_sizes[0] - 1;

  // Workspace: Wbf (128 KB) | fs_h bf16 [H][N][64] (51.2 MB) | el_h, er_h
  // [H][N] (1.6 MB each)
  char* ws = (char*)d_ws;
  unsigned short* Wbf = (unsigned short*)ws;
  unsigned short* fs_h = (unsigned short*)(ws + 128 * 1024);
  size_t fs_bytes = (size_t)n_nodes * NOUT * sizeof(unsigned short);
  float* el_h = (float*)(ws + 128 * 1024 + fs_bytes);
  float* er_h = el_h + (size_t)n_nodes * HEADS;

  k_cast_w<<<64, 256, 0, stream>>>(W, Wbf);
  k_gemm_mfma<<<(n_nodes + 63) / 64, 256, 0, stream>>>(
      feat, Wbf, attn_l, attn_r, fs_h, el_h, er_h, n_nodes);

  int nb16 = (n_nodes + 15) / 16;  // 16-node groups per head
  nb16 += (nb16 & 1);              // even, so the %8 residue mapping is exact
  k_aggregate<<<nb16 * 4, 256, 0, stream>>>(
      row_ptr, col_ind, el_h, er_h, fs_h, out, n_nodes);
}